// Round 13
// baseline (80.305 us; speedup 1.0000x reference)
//
#include <hip/hip_runtime.h>
#include <hip/hip_bf16.h>
#include <cstdint>

#define S4_H 256
#define S4_N 32
#define S4_L 4096
#define S4_B 16
#define S4_T 64
#define S4_C 64

typedef __attribute__((ext_vector_type(8))) short bf16x8;
typedef __attribute__((ext_vector_type(4))) float f32x4;

// compiler + same-wave LDS ordering fence (phase boundary for in-place LDS reuse)
#define S4_LDS_FENCE() asm volatile("s_waitcnt lgkmcnt(0)" ::: "memory")

// round-to-nearest-even f32 -> bf16 (finite inputs) -- manual form (tab/wconv)
__device__ __forceinline__ uint32_t s4_f2bf(float f) {
    uint32_t u = __float_as_uint(f);
    return (u + 0x7fffu + ((u >> 16) & 1u)) >> 16;
}

// packed f32x2 -> bf16x2 via COMPILER intrinsic (emits v_cvt_pk_bf16_f32; RNE,
// bit-identical to s4_f2bf). a -> low16, b -> high16.
__device__ __forceinline__ uint32_t s4_pk2(float a, float b) {
    union { __hip_bfloat162 h; uint32_t u; } cv;
    cv.h = __float22bfloat162_rn(make_float2(a, b));
    return cv.u;
}

// tanh-approx GELU, fast divide (rcp+mul, <=2.5ulp): x*sigmoid(1.59577(x+0.044715x^3))
__device__ __forceinline__ float s4_gelu(float x) {
    float x3 = x * x * x;
    float z = 1.5957691216057308f * fmaf(0.044715f, x3, x);
    float e = __expf(-z);
    return __fdividef(x, 1.0f + e);
}

// sum within each 32-lane half via DPP; result valid in lanes 31 and 63
__device__ __forceinline__ float s4_rowsum32(float v) {
    v += __int_as_float(__builtin_amdgcn_update_dpp(0, __float_as_int(v), 0x111, 0xf, 0xf, false)); // row_shr:1
    v += __int_as_float(__builtin_amdgcn_update_dpp(0, __float_as_int(v), 0x112, 0xf, 0xf, false)); // row_shr:2
    v += __int_as_float(__builtin_amdgcn_update_dpp(0, __float_as_int(v), 0x114, 0xf, 0xf, false)); // row_shr:4
    v += __int_as_float(__builtin_amdgcn_update_dpp(0, __float_as_int(v), 0x118, 0xf, 0xf, false)); // row_shr:8
    v += __int_as_float(__builtin_amdgcn_update_dpp(0, __float_as_int(v), 0x142, 0xf, 0xf, false)); // row_bcast15
    return v;
}

// ---------------- table kernel: per-h E, Toeplitz(K + D*delta0), V tables + w^T ----------------
__global__ __launch_bounds__(64) void s4_tab_kernel(
        const float* __restrict__ log_dt, const float* __restrict__ log_A_real,
        const float* __restrict__ A_imag, const float* __restrict__ C_real,
        const float* __restrict__ C_imag, const float* __restrict__ D,
        float* __restrict__ wT, ushort* __restrict__ Ebf,
        ushort* __restrict__ TMbf, ushort* __restrict__ Vbf) {
    const int h = blockIdx.x, tid = threadIdx.x, n = tid & 31;
    __shared__ float Ksh[S4_T];
    const int idx = h * 32 + n;
    float dt = expf(log_dt[h]);
    float Ar = -expf(log_A_real[idx]);
    float Ai = A_imag[idx];
    float er = expf(dt * Ar);
    float wr = er * cosf(dt * Ai);
    float wi = er * sinf(dt * Ai);
    float inv = 1.0f / (Ar * Ar + Ai * Ai);
    float mr = wr - 1.0f, mi = wi;
    float qr = (mr * Ar + mi * Ai) * inv;
    float qi = (mi * Ar - mr * Ai) * inv;
    float Cr = C_real[idx], Ci = C_imag[idx];
    float cr = 2.0f * (Cr * qr - Ci * qi);    //  2*Re(Chat)
    float ci = -2.0f * (Cr * qi + Ci * qr);   // -2*Im(Chat)
    ushort* Eh = Ebf + h * 4096;
    ushort* Vh = Vbf + h * 4096;
    float pr = 1.0f, pi = 0.0f;               // p = w^t
    for (int t = 0; t < S4_T; ++t) {
        if (tid < 32) {
            Eh[(2 * n) * 64 + (63 - t)]     = (ushort)s4_f2bf(pr);
            Eh[(2 * n + 1) * 64 + (63 - t)] = (ushort)s4_f2bf(pi);
        }
        float kt = s4_rowsum32(fmaf(cr, pr, ci * pi));   // K[t] = 2Re(sum Chat w^t)
        if (tid == 31) Ksh[t] = kt;
        float Qr = pr * wr - pi * wi;          // Q = w^{t+1}
        float Qi = pr * wi + pi * wr;
        if (tid < 32) {
            Vh[t * 64 + 2 * n]     = (ushort)s4_f2bf(fmaf(cr, Qr, ci * Qi));   //  2Re(Chat Q)
            Vh[t * 64 + 2 * n + 1] = (ushort)s4_f2bf(fmaf(ci, Qr, -cr * Qi));  // -2Im(Chat Q)
        }
        pr = Qr; pi = Qi;
    }
    if (tid < 32) { wT[idx] = pr; wT[8192 + idx] = pi; }   // w^64
    __syncthreads();
    const float Dh = D[h];                     // fold skip connection into Toeplitz diagonal
    ushort* TMh = TMbf + h * 4096;
    for (int e = tid; e < 4096; e += 64) {
        int to = e >> 6, ti = e & 63;
        float kv = Ksh[to - ti] + ((to == ti) ? Dh : 0.0f);
        TMh[e] = (ti <= to) ? (ushort)s4_f2bf(kv) : (ushort)0;
    }
}

// ---------------- W f32 -> octet-interleaved bf16: Wp[k/8][m][8] ----------------
__global__ __launch_bounds__(256) void s4_wconv(const float* __restrict__ W,
                                               ushort* __restrict__ Wp) {
    const int m = threadIdx.x, ko = blockIdx.x;
    const float* src = W + (size_t)m * S4_H + ko * 8;
    float4 a = *(const float4*)src;
    float4 b = *(const float4*)(src + 4);
    uint4 pk;
    pk.x = s4_f2bf(a.x) | (s4_f2bf(a.y) << 16);
    pk.y = s4_f2bf(a.z) | (s4_f2bf(a.w) << 16);
    pk.z = s4_f2bf(b.x) | (s4_f2bf(b.y) << 16);
    pk.w = s4_f2bf(b.z) | (s4_f2bf(b.w) << 16);
    *(uint4*)(Wp + ((size_t)ko * S4_H + m) * 8) = pk;
}

// ---------------- barrier-free scan: one WAVE per (b,h), 2 waves/block ----------------
// R12-proven structure; VALU slimmed: compiler cvt_pk packs + fast divide gelu.
// LDS slice per wave: U (bf16, swizzled) -> S -> X in place; fences at phase bounds.
__global__ __launch_bounds__(128, 4) void s4_scan_fused(
        const float* __restrict__ u, const float* __restrict__ wT,
        const ushort* __restrict__ Ebf, const ushort* __restrict__ TMbf,
        const ushort* __restrict__ Vbf,
        uint32_t* __restrict__ g) {
    __shared__ char Ssh[2][8192];      // per-wave slice
    const int tid = threadIdx.x;
    const int wv = tid >> 6, lane = tid & 63;
    const int l15 = lane & 15, lg = lane >> 4;
    const int bh = blockIdx.x * 2 + wv;
    const int h = bh & (S4_H - 1);
    char* sbase = Ssh[wv];
    const float* up = u + (size_t)bh * S4_L;

    // ---- stage U: 16 lane-contiguous float4 loads -> bf16 LDS ----
    #pragma unroll
    for (int it = 0; it < 16; ++it) {
        int i = it * 64 + lane;                 // float4 index, lanes contiguous
        float4 v = ((const float4*)up)[i];
        uint2 pk;
        pk.x = s4_pk2(v.x, v.y);
        pk.y = s4_pk2(v.z, v.w);
        int o = i * 8;
        *(uint2*)(sbase + (o ^ (((o >> 7) & 7) << 4))) = pk;
    }
    S4_LDS_FENCE();   // staging stores -> fragment loads

    // ---- U fragments from LDS ----
    bf16x8 ufr[4][2];
    #pragma unroll
    for (int ct = 0; ct < 4; ++ct) {
        int c = ct * 16 + l15, swz = (c & 7) << 4;
        ufr[ct][0] = *(const bf16x8*)(sbase + ((c * 128 + lg * 16) ^ swz));
        ufr[ct][1] = *(const bf16x8*)(sbase + ((c * 128 + 64 + lg * 16) ^ swz));
    }

    // ---- phase 1: S = E @ U (full 64x64 this wave) ----
    const size_t trow = (size_t)h * 4096 + (size_t)l15 * 64 + lg * 8;
    f32x4 sac[4][4] = {};
    #pragma unroll
    for (int q = 0; q < 2; ++q)
        #pragma unroll
        for (int mt = 0; mt < 4; ++mt) {
            bf16x8 eA = *(const bf16x8*)(Ebf + trow + mt * 1024 + q * 32);
            #pragma unroll
            for (int nt = 0; nt < 4; ++nt)
                sac[mt][nt] = __builtin_amdgcn_mfma_f32_16x16x32_bf16(eA, ufr[nt][q], sac[mt][nt], 0, 0, 0);
        }
    // S -> LDS bf16 [c][r] over U (all U already consumed into regs)
    #pragma unroll
    for (int mt = 0; mt < 4; ++mt)
        #pragma unroll
        for (int nt = 0; nt < 4; ++nt) {
            int c = nt * 16 + l15;
            int byt = (c * 128 + mt * 32 + lg * 8) ^ ((c & 7) << 4);
            uint2 pk;
            pk.x = s4_pk2(sac[mt][nt][0], sac[mt][nt][1]);
            pk.y = s4_pk2(sac[mt][nt][2], sac[mt][nt][3]);
            *(uint2*)(sbase + byt) = pk;
        }
    S4_LDS_FENCE();   // S-pack stores -> phase-2 loads

    // ---- hoist V-table loads: latency hides under the serial phase below ----
    bf16x8 v0f[4], v1f[4];
    #pragma unroll
    for (int mt = 0; mt < 4; ++mt) {
        v0f[mt] = *(const bf16x8*)(Vbf + trow + mt * 1024);
        v1f[mt] = *(const bf16x8*)(Vbf + trow + mt * 1024 + 32);
    }

    // ---- phase 2 (lanes 0-31): read S[c], overwrite with X[c]=pre-state, update x ----
    if (lane < 32) {
        float wtr = wT[h * 32 + lane], wti = wT[8192 + h * 32 + lane];
        float xr = 0.f, xi = 0.f;
        #pragma unroll
        for (int c = 0; c < S4_C; ++c) {
            int off = (c * 128 + lane * 4) ^ ((c & 7) << 4);
            uint32_t sp = *(uint32_t*)(sbase + off);
            *(uint32_t*)(sbase + off) = s4_pk2(xr, xi);
            float sr = __uint_as_float(sp << 16);
            float si = __uint_as_float(sp & 0xffff0000u);
            float nr = fmaf(wtr, xr, fmaf(-wti, xi, sr));
            float ni = fmaf(wtr, xi, fmaf(wti, xr, si));
            xr = nr; xi = ni;
        }
    }
    S4_LDS_FENCE();   // phase-2 X stores -> X fragment loads

    // ---- X fragments (same-wave readback, no barrier) ----
    bf16x8 xb[4][2];
    #pragma unroll
    for (int ct = 0; ct < 4; ++ct) {
        int c = ct * 16 + l15;
        #pragma unroll
        for (int q = 0; q < 2; ++q)
            xb[ct][q] = *(const bf16x8*)(sbase + ((c * 128 + q * 64 + lg * 16) ^ ((c & 7) << 4)));
    }

    // ---- phase 3 + gelu epilogue (D-skip already inside TM diagonal) ----
    uint32_t* gp = g + (size_t)bh * (S4_L / 2);
    #pragma unroll
    for (int mt = 0; mt < 4; ++mt) {
        bf16x8 t0f = *(const bf16x8*)(TMbf + trow + mt * 1024);
        bf16x8 t1f = {};
        if (mt >= 2) t1f = *(const bf16x8*)(TMbf + trow + mt * 1024 + 32);
        #pragma unroll
        for (int ct = 0; ct < 4; ++ct) {
            f32x4 y = {0.f, 0.f, 0.f, 0.f};
            y = __builtin_amdgcn_mfma_f32_16x16x32_bf16(t0f, ufr[ct][0], y, 0, 0, 0);
            if (mt >= 2)   // Toeplitz rows < 32 have zero k>=32 block
                y = __builtin_amdgcn_mfma_f32_16x16x32_bf16(t1f, ufr[ct][1], y, 0, 0, 0);
            y = __builtin_amdgcn_mfma_f32_16x16x32_bf16(v0f[mt], xb[ct][0], y, 0, 0, 0);
            y = __builtin_amdgcn_mfma_f32_16x16x32_bf16(v1f[mt], xb[ct][1], y, 0, 0, 0);
            int c = ct * 16 + l15;
            uint2 opk;
            opk.x = s4_pk2(s4_gelu(y[0]), s4_gelu(y[1]));
            opk.y = s4_pk2(s4_gelu(y[2]), s4_gelu(y[3]));
            *(uint2*)(gp + c * 32 + mt * 8 + lg * 2) = opk;
        }
    }
}

// ---------------- fused MFMA GEMM: out[b] = W @ G[b] + bias (unchanged, proven) ----------------
__global__ __launch_bounds__(256) void s4_gemm_mfma(
        const ushort* __restrict__ g,     // bf16 (B,H,L)
        const ushort* __restrict__ Wp,    // octet-interleaved W
        const float* __restrict__ bias, float* __restrict__ out) {
    __shared__ char GlB[32768];           // [64 l][32 ho][8 h] bf16, swizzled
    const int tid = threadIdx.x;
    const int wv = tid >> 6, lane = tid & 63;
    const int l15 = lane & 15, lg = lane >> 4;
    const int b = blockIdx.y;
    const int l0 = blockIdx.x << 6;       // 64 l cols per block

    {
        const int ho = tid >> 3, lp = tid & 7;
        const ushort* gb = g + ((size_t)(b * S4_H) + ho * 8) * S4_L + l0;
        #pragma unroll
        for (int it = 0; it < 4; ++it) {
            const int ll = 2 * (lp + 8 * it);     // even l_local
            uint32_t r[8];
            #pragma unroll
            for (int i = 0; i < 8; ++i)
                r[i] = *(const uint32_t*)(gb + (size_t)i * S4_L + ll);
            uint4 lo, hi;
            lo.x = (r[0] & 0xffffu) | (r[1] << 16);
            lo.y = (r[2] & 0xffffu) | (r[3] << 16);
            lo.z = (r[4] & 0xffffu) | (r[5] << 16);
            lo.w = (r[6] & 0xffffu) | (r[7] << 16);
            hi.x = (r[0] >> 16) | (r[1] & 0xffff0000u);
            hi.y = (r[2] >> 16) | (r[3] & 0xffff0000u);
            hi.z = (r[4] >> 16) | (r[5] & 0xffff0000u);
            hi.w = (r[6] >> 16) | (r[7] & 0xffff0000u);
            *(uint4*)(GlB + ll * 512 + ((ho ^ (ll & 15)) << 4)) = lo;
            *(uint4*)(GlB + (ll + 1) * 512 + ((ho ^ ((ll + 1) & 15)) << 4)) = hi;
        }
    }
    __syncthreads();

    f32x4 acc[4][4] = {};
    const ushort* wpl = Wp + (size_t)(64 * wv + l15) * 8;
    #pragma unroll
    for (int kb = 0; kb < 8; ++kb) {
        const int ko = kb * 4 + lg;
        bf16x8 aF[4], bF[4];
        #pragma unroll
        for (int i = 0; i < 4; ++i)
            aF[i] = *(const bf16x8*)(wpl + ((size_t)ko * S4_H + i * 16) * 8);
        #pragma unroll
        for (int j = 0; j < 4; ++j)
            bF[j] = *(const bf16x8*)(GlB + (j * 16 + l15) * 512 + ((ko ^ l15) << 4));
        #pragma unroll
        for (int i = 0; i < 4; ++i)
            #pragma unroll
            for (int j = 0; j < 4; ++j)
                acc[i][j] = __builtin_amdgcn_mfma_f32_16x16x32_bf16(aF[i], bF[j], acc[i][j], 0, 0, 0);
    }

    float* ob = out + ((size_t)(b * S4_H) + 64 * wv) * S4_L + l0;
    #pragma unroll
    for (int i = 0; i < 4; ++i) {
        #pragma unroll
        for (int jj = 0; jj < 4; ++jj) {
            const int mrow = i * 16 + lg * 4 + jj;
            const float bv = bias[64 * wv + mrow];
            float* orow = ob + (size_t)mrow * S4_L + l15;
            #pragma unroll
            for (int j = 0; j < 4; ++j)
                orow[j * 16] = acc[i][j][jj] + bv;
        }
    }
}

extern "C" void kernel_launch(void* const* d_in, const int* in_sizes, int n_in,
                              void* d_out, int out_size, void* d_ws, size_t ws_size,
                              hipStream_t stream) {
    const float* inp        = (const float*)d_in[0]; // (B,CIN,F,L) == (B,H,L)
    const float* log_dt     = (const float*)d_in[1];
    const float* log_A_real = (const float*)d_in[2];
    const float* A_imag     = (const float*)d_in[3];
    const float* C_real     = (const float*)d_in[4];
    const float* C_imag     = (const float*)d_in[5];
    const float* D          = (const float*)d_in[6];
    const float* W_out      = (const float*)d_in[7];
    const float* b_out      = (const float*)d_in[8];
    float* out = (float*)d_out;

    char* wsc = (char*)d_ws;
    size_t off = 0;
    float* wT     = (float*)(wsc + off);  off += (64 << 10);       // 64 KB
    ushort* Ebf   = (ushort*)(wsc + off); off += (2 << 20);        // 2 MB
    ushort* TMbf  = (ushort*)(wsc + off); off += (2 << 20);        // 2 MB
    ushort* Vbf   = (ushort*)(wsc + off); off += (2 << 20);        // 2 MB
    ushort* Wp    = (ushort*)(wsc + off); off += (128 << 10);      // 128 KB
    uint32_t* g   = (uint32_t*)(wsc + off);                         // 33.5 MB bf16 (B,H,L)

    hipLaunchKernelGGL(s4_tab_kernel, dim3(S4_H), dim3(64), 0, stream,
                       log_dt, log_A_real, A_imag, C_real, C_imag, D, wT, Ebf, TMbf, Vbf);
    hipLaunchKernelGGL(s4_wconv, dim3(32), dim3(256), 0, stream, W_out, Wp);
    hipLaunchKernelGGL(s4_scan_fused, dim3(S4_B * S4_H / 2), dim3(128), 0, stream,
                       inp, wT, Ebf, TMbf, Vbf, g);
    hipLaunchKernelGGL(s4_gemm_mfma, dim3(S4_L / 64, S4_B), dim3(256), 0, stream,
                       (const ushort*)g, Wp, b_out, out);
}

// Round 14
// 79.210 us; speedup vs baseline: 1.0138x; 1.0138x over previous
//
#include <hip/hip_runtime.h>
#include <hip/hip_bf16.h>
#include <cstdint>

#define S4_H 256
#define S4_N 32
#define S4_L 4096
#define S4_B 16
#define S4_T 64
#define S4_C 64

typedef __attribute__((ext_vector_type(8))) short bf16x8;
typedef __attribute__((ext_vector_type(4))) float f32x4;

// compiler + same-wave LDS ordering fence (phase boundary for in-place LDS reuse)
#define S4_LDS_FENCE() asm volatile("s_waitcnt lgkmcnt(0)" ::: "memory")

// round-to-nearest-even f32 -> bf16 (finite inputs) -- manual form (tab/wconv)
__device__ __forceinline__ uint32_t s4_f2bf(float f) {
    uint32_t u = __float_as_uint(f);
    return (u + 0x7fffu + ((u >> 16) & 1u)) >> 16;
}

// packed f32x2 -> bf16x2 via COMPILER intrinsic (emits v_cvt_pk_bf16_f32; RNE)
__device__ __forceinline__ uint32_t s4_pk2(float a, float b) {
    union { __hip_bfloat162 h; uint32_t u; } cv;
    cv.h = __float22bfloat162_rn(make_float2(a, b));
    return cv.u;
}

// tanh-approx GELU, fast divide (rcp+mul, <=2.5ulp)
__device__ __forceinline__ float s4_gelu(float x) {
    float x3 = x * x * x;
    float z = 1.5957691216057308f * fmaf(0.044715f, x3, x);
    float e = __expf(-z);
    return __fdividef(x, 1.0f + e);
}

// sum within each 32-lane half via DPP; result valid in lanes 31 and 63
__device__ __forceinline__ float s4_rowsum32(float v) {
    v += __int_as_float(__builtin_amdgcn_update_dpp(0, __float_as_int(v), 0x111, 0xf, 0xf, false)); // row_shr:1
    v += __int_as_float(__builtin_amdgcn_update_dpp(0, __float_as_int(v), 0x112, 0xf, 0xf, false)); // row_shr:2
    v += __int_as_float(__builtin_amdgcn_update_dpp(0, __float_as_int(v), 0x114, 0xf, 0xf, false)); // row_shr:4
    v += __int_as_float(__builtin_amdgcn_update_dpp(0, __float_as_int(v), 0x118, 0xf, 0xf, false)); // row_shr:8
    v += __int_as_float(__builtin_amdgcn_update_dpp(0, __float_as_int(v), 0x142, 0xf, 0xf, false)); // row_bcast15
    return v;
}

// ---------------- table kernel: per-h E, Toeplitz(K + D*delta0), V tables + w^T ----------------
__global__ __launch_bounds__(64) void s4_tab_kernel(
        const float* __restrict__ log_dt, const float* __restrict__ log_A_real,
        const float* __restrict__ A_imag, const float* __restrict__ C_real,
        const float* __restrict__ C_imag, const float* __restrict__ D,
        float* __restrict__ wT, ushort* __restrict__ Ebf,
        ushort* __restrict__ TMbf, ushort* __restrict__ Vbf) {
    const int h = blockIdx.x, tid = threadIdx.x, n = tid & 31;
    __shared__ float Ksh[S4_T];
    const int idx = h * 32 + n;
    float dt = expf(log_dt[h]);
    float Ar = -expf(log_A_real[idx]);
    float Ai = A_imag[idx];
    float er = expf(dt * Ar);
    float wr = er * cosf(dt * Ai);
    float wi = er * sinf(dt * Ai);
    float inv = 1.0f / (Ar * Ar + Ai * Ai);
    float mr = wr - 1.0f, mi = wi;
    float qr = (mr * Ar + mi * Ai) * inv;
    float qi = (mi * Ar - mr * Ai) * inv;
    float Cr = C_real[idx], Ci = C_imag[idx];
    float cr = 2.0f * (Cr * qr - Ci * qi);    //  2*Re(Chat)
    float ci = -2.0f * (Cr * qi + Ci * qr);   // -2*Im(Chat)
    ushort* Eh = Ebf + h * 4096;
    ushort* Vh = Vbf + h * 4096;
    float pr = 1.0f, pi = 0.0f;               // p = w^t
    for (int t = 0; t < S4_T; ++t) {
        if (tid < 32) {
            Eh[(2 * n) * 64 + (63 - t)]     = (ushort)s4_f2bf(pr);
            Eh[(2 * n + 1) * 64 + (63 - t)] = (ushort)s4_f2bf(pi);
        }
        float kt = s4_rowsum32(fmaf(cr, pr, ci * pi));   // K[t] = 2Re(sum Chat w^t)
        if (tid == 31) Ksh[t] = kt;
        float Qr = pr * wr - pi * wi;          // Q = w^{t+1}
        float Qi = pr * wi + pi * wr;
        if (tid < 32) {
            Vh[t * 64 + 2 * n]     = (ushort)s4_f2bf(fmaf(cr, Qr, ci * Qi));   //  2Re(Chat Q)
            Vh[t * 64 + 2 * n + 1] = (ushort)s4_f2bf(fmaf(ci, Qr, -cr * Qi));  // -2Im(Chat Q)
        }
        pr = Qr; pi = Qi;
    }
    if (tid < 32) { wT[idx] = pr; wT[8192 + idx] = pi; }   // w^64
    __syncthreads();
    const float Dh = D[h];                     // fold skip connection into Toeplitz diagonal
    ushort* TMh = TMbf + h * 4096;
    for (int e = tid; e < 4096; e += 64) {
        int to = e >> 6, ti = e & 63;
        float kv = Ksh[to - ti] + ((to == ti) ? Dh : 0.0f);
        TMh[e] = (ti <= to) ? (ushort)s4_f2bf(kv) : (ushort)0;
    }
}

// ---------------- W f32 -> octet-interleaved bf16: Wp[k/8][m][8] ----------------
__global__ __launch_bounds__(256) void s4_wconv(const float* __restrict__ W,
                                               ushort* __restrict__ Wp) {
    const int m = threadIdx.x, ko = blockIdx.x;
    const float* src = W + (size_t)m * S4_H + ko * 8;
    float4 a = *(const float4*)src;
    float4 b = *(const float4*)(src + 4);
    uint4 pk;
    pk.x = s4_f2bf(a.x) | (s4_f2bf(a.y) << 16);
    pk.y = s4_f2bf(a.z) | (s4_f2bf(a.w) << 16);
    pk.z = s4_f2bf(b.x) | (s4_f2bf(b.y) << 16);
    pk.w = s4_f2bf(b.z) | (s4_f2bf(b.w) << 16);
    *(uint4*)(Wp + ((size_t)ko * S4_H + m) * 8) = pk;
}

// ---------------- barrier-free scan: one WAVE per (b,h), 2 waves/block ----------------
// Latency-batching round: __launch_bounds__(128,2) lifts VGPR cap 64->256 so
// (a) all 16 staging loads are in flight at once, (b) phase-2 prefetches S in
// 16-deep register chunks (exposed LDS latency 64x120 -> 4x120 cycles).
__global__ __launch_bounds__(128, 2) void s4_scan_fused(
        const float* __restrict__ u, const float* __restrict__ wT,
        const ushort* __restrict__ Ebf, const ushort* __restrict__ TMbf,
        const ushort* __restrict__ Vbf,
        uint32_t* __restrict__ g) {
    __shared__ char Ssh[2][8192];      // per-wave slice: U -> S -> X (in place)
    const int tid = threadIdx.x;
    const int wv = tid >> 6, lane = tid & 63;
    const int l15 = lane & 15, lg = lane >> 4;
    const int bh = blockIdx.x * 2 + wv;
    const int h = bh & (S4_H - 1);
    char* sbase = Ssh[wv];
    const float* up = u + (size_t)bh * S4_L;

    // ---- stage U: issue ALL 16 coalesced float4 loads, then pack+write ----
    {
        float4 vbuf[16];
        #pragma unroll
        for (int it = 0; it < 16; ++it)
            vbuf[it] = ((const float4*)up)[it * 64 + lane];
        #pragma unroll
        for (int it = 0; it < 16; ++it) {
            int i = it * 64 + lane;
            uint2 pk;
            pk.x = s4_pk2(vbuf[it].x, vbuf[it].y);
            pk.y = s4_pk2(vbuf[it].z, vbuf[it].w);
            int o = i * 8;
            *(uint2*)(sbase + (o ^ (((o >> 7) & 7) << 4))) = pk;
        }
    }
    S4_LDS_FENCE();   // staging stores -> fragment loads

    // ---- U fragments from LDS ----
    bf16x8 ufr[4][2];
    #pragma unroll
    for (int ct = 0; ct < 4; ++ct) {
        int c = ct * 16 + l15, swz = (c & 7) << 4;
        ufr[ct][0] = *(const bf16x8*)(sbase + ((c * 128 + lg * 16) ^ swz));
        ufr[ct][1] = *(const bf16x8*)(sbase + ((c * 128 + 64 + lg * 16) ^ swz));
    }

    // ---- phase 1: S = E @ U (full 64x64 this wave) ----
    const size_t trow = (size_t)h * 4096 + (size_t)l15 * 64 + lg * 8;
    f32x4 sac[4][4] = {};
    #pragma unroll
    for (int q = 0; q < 2; ++q)
        #pragma unroll
        for (int mt = 0; mt < 4; ++mt) {
            bf16x8 eA = *(const bf16x8*)(Ebf + trow + mt * 1024 + q * 32);
            #pragma unroll
            for (int nt = 0; nt < 4; ++nt)
                sac[mt][nt] = __builtin_amdgcn_mfma_f32_16x16x32_bf16(eA, ufr[nt][q], sac[mt][nt], 0, 0, 0);
        }
    // S -> LDS bf16 [c][r] over U
    #pragma unroll
    for (int mt = 0; mt < 4; ++mt)
        #pragma unroll
        for (int nt = 0; nt < 4; ++nt) {
            int c = nt * 16 + l15;
            int byt = (c * 128 + mt * 32 + lg * 8) ^ ((c & 7) << 4);
            uint2 pk;
            pk.x = s4_pk2(sac[mt][nt][0], sac[mt][nt][1]);
            pk.y = s4_pk2(sac[mt][nt][2], sac[mt][nt][3]);
            *(uint2*)(sbase + byt) = pk;
        }
    S4_LDS_FENCE();   // S-pack stores -> phase-2 loads

    // ---- hoist V-table loads: latency hides under the serial phase below ----
    bf16x8 v0f[4], v1f[4];
    #pragma unroll
    for (int mt = 0; mt < 4; ++mt) {
        v0f[mt] = *(const bf16x8*)(Vbf + trow + mt * 1024);
        v1f[mt] = *(const bf16x8*)(Vbf + trow + mt * 1024 + 32);
    }

    // ---- phase 2 (lanes 0-31): chunked register prefetch of S, X in place ----
    if (lane < 32) {
        float wtr = wT[h * 32 + lane], wti = wT[8192 + h * 32 + lane];
        float xr = 0.f, xi = 0.f;
        #pragma unroll
        for (int gq = 0; gq < 4; ++gq) {
            uint32_t sbuf[16];
            #pragma unroll
            for (int j = 0; j < 16; ++j) {          // batch-issue 16 ds_reads
                int c = gq * 16 + j;
                sbuf[j] = *(uint32_t*)(sbase + ((c * 128 + lane * 4) ^ ((c & 7) << 4)));
            }
            #pragma unroll
            for (int j = 0; j < 16; ++j) {          // consume + overwrite with X
                int c = gq * 16 + j;
                int off = (c * 128 + lane * 4) ^ ((c & 7) << 4);
                *(uint32_t*)(sbase + off) = s4_pk2(xr, xi);
                float sr = __uint_as_float(sbuf[j] << 16);
                float si = __uint_as_float(sbuf[j] & 0xffff0000u);
                float nr = fmaf(wtr, xr, fmaf(-wti, xi, sr));
                float ni = fmaf(wtr, xi, fmaf(wti, xr, si));
                xr = nr; xi = ni;
            }
        }
    }
    S4_LDS_FENCE();   // phase-2 X stores -> X fragment loads

    // ---- X fragments (same-wave readback, no barrier) ----
    bf16x8 xb[4][2];
    #pragma unroll
    for (int ct = 0; ct < 4; ++ct) {
        int c = ct * 16 + l15;
        #pragma unroll
        for (int q = 0; q < 2; ++q)
            xb[ct][q] = *(const bf16x8*)(sbase + ((c * 128 + q * 64 + lg * 16) ^ ((c & 7) << 4)));
    }

    // ---- phase 3 + gelu epilogue (D-skip already inside TM diagonal) ----
    uint32_t* gp = g + (size_t)bh * (S4_L / 2);
    #pragma unroll
    for (int mt = 0; mt < 4; ++mt) {
        bf16x8 t0f = *(const bf16x8*)(TMbf + trow + mt * 1024);
        bf16x8 t1f = {};
        if (mt >= 2) t1f = *(const bf16x8*)(TMbf + trow + mt * 1024 + 32);
        #pragma unroll
        for (int ct = 0; ct < 4; ++ct) {
            f32x4 y = {0.f, 0.f, 0.f, 0.f};
            y = __builtin_amdgcn_mfma_f32_16x16x32_bf16(t0f, ufr[ct][0], y, 0, 0, 0);
            if (mt >= 2)   // Toeplitz rows < 32 have zero k>=32 block
                y = __builtin_amdgcn_mfma_f32_16x16x32_bf16(t1f, ufr[ct][1], y, 0, 0, 0);
            y = __builtin_amdgcn_mfma_f32_16x16x32_bf16(v0f[mt], xb[ct][0], y, 0, 0, 0);
            y = __builtin_amdgcn_mfma_f32_16x16x32_bf16(v1f[mt], xb[ct][1], y, 0, 0, 0);
            int c = ct * 16 + l15;
            uint2 opk;
            opk.x = s4_pk2(s4_gelu(y[0]), s4_gelu(y[1]));
            opk.y = s4_pk2(s4_gelu(y[2]), s4_gelu(y[3]));
            *(uint2*)(gp + c * 32 + mt * 8 + lg * 2) = opk;
        }
    }
}

// ---------------- fused MFMA GEMM: out[b] = W @ G[b] + bias (unchanged, proven) ----------------
__global__ __launch_bounds__(256) void s4_gemm_mfma(
        const ushort* __restrict__ g,     // bf16 (B,H,L)
        const ushort* __restrict__ Wp,    // octet-interleaved W
        const float* __restrict__ bias, float* __restrict__ out) {
    __shared__ char GlB[32768];           // [64 l][32 ho][8 h] bf16, swizzled
    const int tid = threadIdx.x;
    const int wv = tid >> 6, lane = tid & 63;
    const int l15 = lane & 15, lg = lane >> 4;
    const int b = blockIdx.y;
    const int l0 = blockIdx.x << 6;       // 64 l cols per block

    {
        const int ho = tid >> 3, lp = tid & 7;
        const ushort* gb = g + ((size_t)(b * S4_H) + ho * 8) * S4_L + l0;
        #pragma unroll
        for (int it = 0; it < 4; ++it) {
            const int ll = 2 * (lp + 8 * it);     // even l_local
            uint32_t r[8];
            #pragma unroll
            for (int i = 0; i < 8; ++i)
                r[i] = *(const uint32_t*)(gb + (size_t)i * S4_L + ll);
            uint4 lo, hi;
            lo.x = (r[0] & 0xffffu) | (r[1] << 16);
            lo.y = (r[2] & 0xffffu) | (r[3] << 16);
            lo.z = (r[4] & 0xffffu) | (r[5] << 16);
            lo.w = (r[6] & 0xffffu) | (r[7] << 16);
            hi.x = (r[0] >> 16) | (r[1] & 0xffff0000u);
            hi.y = (r[2] >> 16) | (r[3] & 0xffff0000u);
            hi.z = (r[4] >> 16) | (r[5] & 0xffff0000u);
            hi.w = (r[6] >> 16) | (r[7] & 0xffff0000u);
            *(uint4*)(GlB + ll * 512 + ((ho ^ (ll & 15)) << 4)) = lo;
            *(uint4*)(GlB + (ll + 1) * 512 + ((ho ^ ((ll + 1) & 15)) << 4)) = hi;
        }
    }
    __syncthreads();

    f32x4 acc[4][4] = {};
    const ushort* wpl = Wp + (size_t)(64 * wv + l15) * 8;
    #pragma unroll
    for (int kb = 0; kb < 8; ++kb) {
        const int ko = kb * 4 + lg;
        bf16x8 aF[4], bF[4];
        #pragma unroll
        for (int i = 0; i < 4; ++i)
            aF[i] = *(const bf16x8*)(wpl + ((size_t)ko * S4_H + i * 16) * 8);
        #pragma unroll
        for (int j = 0; j < 4; ++j)
            bF[j] = *(const bf16x8*)(GlB + (j * 16 + l15) * 512 + ((ko ^ l15) << 4));
        #pragma unroll
        for (int i = 0; i < 4; ++i)
            #pragma unroll
            for (int j = 0; j < 4; ++j)
                acc[i][j] = __builtin_amdgcn_mfma_f32_16x16x32_bf16(aF[i], bF[j], acc[i][j], 0, 0, 0);
    }

    float* ob = out + ((size_t)(b * S4_H) + 64 * wv) * S4_L + l0;
    #pragma unroll
    for (int i = 0; i < 4; ++i) {
        #pragma unroll
        for (int jj = 0; jj < 4; ++jj) {
            const int mrow = i * 16 + lg * 4 + jj;
            const float bv = bias[64 * wv + mrow];
            float* orow = ob + (size_t)mrow * S4_L + l15;
            #pragma unroll
            for (int j = 0; j < 4; ++j)
                orow[j * 16] = acc[i][j][jj] + bv;
        }
    }
}

extern "C" void kernel_launch(void* const* d_in, const int* in_sizes, int n_in,
                              void* d_out, int out_size, void* d_ws, size_t ws_size,
                              hipStream_t stream) {
    const float* inp        = (const float*)d_in[0]; // (B,CIN,F,L) == (B,H,L)
    const float* log_dt     = (const float*)d_in[1];
    const float* log_A_real = (const float*)d_in[2];
    const float* A_imag     = (const float*)d_in[3];
    const float* C_real     = (const float*)d_in[4];
    const float* C_imag     = (const float*)d_in[5];
    const float* D          = (const float*)d_in[6];
    const float* W_out      = (const float*)d_in[7];
    const float* b_out      = (const float*)d_in[8];
    float* out = (float*)d_out;

    char* wsc = (char*)d_ws;
    size_t off = 0;
    float* wT     = (float*)(wsc + off);  off += (64 << 10);       // 64 KB
    ushort* Ebf   = (ushort*)(wsc + off); off += (2 << 20);        // 2 MB
    ushort* TMbf  = (ushort*)(wsc + off); off += (2 << 20);        // 2 MB
    ushort* Vbf   = (ushort*)(wsc + off); off += (2 << 20);        // 2 MB
    ushort* Wp    = (ushort*)(wsc + off); off += (128 << 10);      // 128 KB
    uint32_t* g   = (uint32_t*)(wsc + off);                         // 33.5 MB bf16 (B,H,L)

    hipLaunchKernelGGL(s4_tab_kernel, dim3(S4_H), dim3(64), 0, stream,
                       log_dt, log_A_real, A_imag, C_real, C_imag, D, wT, Ebf, TMbf, Vbf);
    hipLaunchKernelGGL(s4_wconv, dim3(32), dim3(256), 0, stream, W_out, Wp);
    hipLaunchKernelGGL(s4_scan_fused, dim3(S4_B * S4_H / 2), dim3(128), 0, stream,
                       inp, wT, Ebf, TMbf, Vbf, g);
    hipLaunchKernelGGL(s4_gemm_mfma, dim3(S4_L / 64, S4_B), dim3(256), 0, stream,
                       (const ushort*)g, Wp, b_out, out);
}